// Round 3
// baseline (254.507 us; speedup 1.0000x reference)
//
#include <hip/hip_runtime.h>

// GroupDense: y[row, g*64+v] = relu( sum_u x[row, g*64+u] * K[g, u, v] )
// x: [16384, 4096] fp32, K: [64, 64, 64] fp32, out: [16384, 4096] fp32.
//
// Design: lane = row, wave = 16-column quarter. K comes through the SCALAR
// pipe (s_load_dwordx16, wave-uniform -> free 64-lane broadcast), so the LDS
// pipe only carries x once (staged via global_load_lds with XOR-swizzled
// source; per-lane-row b128 reads hit the 8-pass bank floor).
// Per 4-u step: 4 s_load_dwordx16 + lgkmcnt(0) + 64 v_fmac (SGPR x VGPR).
// Block = 256 threads = 4 waves = 64 rows x all 64 cols of one group.

constexpr int C_DIM = 4096;
constexpr int NGROUP = 64;
constexpr int ROWS_PER_BLOCK = 64;
constexpr int THREADS = 256;

typedef __attribute__((address_space(3))) void lds_void_t;
typedef const __attribute__((address_space(1))) void gbl_void_t;
typedef float f32x16 __attribute__((ext_vector_type(16)));

__global__ __launch_bounds__(THREADS, 4) void group_dense_kernel(
    const float* __restrict__ x,
    const float* __restrict__ k,
    float* __restrict__ out)
{
    __shared__ float Xs[ROWS_PER_BLOCK * 64]; // 16 KiB

    const int bid = blockIdx.x;
    const int g = bid >> 8;          // row-blocks fastest -> K[g] stays hot
    const int rb = bid & 255;
    const int row0 = rb * ROWS_PER_BLOCK;
    const int tid = threadIdx.x;
    const int lane = tid & 63;
    const int wave = tid >> 6;       // 0..3 -> column quarter

    // ---- stage x rows [row0, row0+64) g-slice into LDS ----
    // slot s of row r holds data-chunk s ^ (r & 15)  (16B chunks)
    {
        const int l4 = lane >> 4;    // row within 4-row call
        const int ch = lane & 15;    // dest chunk slot
        #pragma unroll
        for (int c = 0; c < 4; ++c) {
            const int rl = wave * 16 + c * 4 + l4;
            const int chunk = ch ^ (rl & 15);            // pre-swizzled source
            const float* src = x + (size_t)(row0 + rl) * C_DIM + g * 64 + chunk * 4;
            float* dst = &Xs[(wave * 16 + c * 4) * 64];  // wave-uniform, linear
            __builtin_amdgcn_global_load_lds((gbl_void_t*)src, (lds_void_t*)dst, 16, 0, 0);
        }
    }
    __syncthreads();

    // ---- lane reads its own row into 64 VGPRs (b128 at bank floor) ----
    float xr[64];
    #pragma unroll
    for (int d = 0; d < 16; ++d) {
        const float4 t = *reinterpret_cast<const float4*>(
            &Xs[lane * 64 + ((d ^ (lane & 15)) * 4)]);
        xr[d * 4 + 0] = t.x; xr[d * 4 + 1] = t.y;
        xr[d * 4 + 2] = t.z; xr[d * 4 + 3] = t.w;
    }

    // ---- K via scalar loads: this wave's 16-column slice ----
    const int woff = __builtin_amdgcn_readfirstlane(wave * 16);
    const float* kp = k + (size_t)g * 4096 + woff;

    float acc[16] = {};

    #pragma unroll
    for (int q = 0; q < 16; ++q) {           // u = 4q .. 4q+3
        f32x16 k0, k1, k2, k3;
        const float* kq = kp + q * 256;      // 4 K-rows = 1 KiB
        asm volatile("s_load_dwordx16 %0, %1, 0x0"   : "=s"(k0) : "s"(kq));
        asm volatile("s_load_dwordx16 %0, %1, 0x100" : "=s"(k1) : "s"(kq));
        asm volatile("s_load_dwordx16 %0, %1, 0x200" : "=s"(k2) : "s"(kq));
        asm volatile("s_load_dwordx16 %0, %1, 0x300" : "=s"(k3) : "s"(kq));
        asm volatile("s_waitcnt lgkmcnt(0)" ::: "memory");
        __builtin_amdgcn_sched_barrier(0);   // rule #18: no FMA hoist past wait

        const float x0 = xr[q * 4 + 0], x1 = xr[q * 4 + 1];
        const float x2 = xr[q * 4 + 2], x3 = xr[q * 4 + 3];
        #pragma unroll
        for (int j = 0; j < 16; ++j) {       // u-ascending order per output
            acc[j] = fmaf(x0, k0[j], acc[j]);
            acc[j] = fmaf(x1, k1[j], acc[j]);
            acc[j] = fmaf(x2, k2[j], acc[j]);
            acc[j] = fmaf(x3, k3[j], acc[j]);
        }
        __builtin_amdgcn_sched_barrier(0);   // box the iteration: bound SGPRs
    }

    // ---- ReLU + store: lane writes its row's 16-col slice (full 64B) ----
    float* op = out + (size_t)(row0 + lane) * C_DIM + g * 64 + woff;
    #pragma unroll
    for (int c = 0; c < 4; ++c) {
        float4 o;
        o.x = fmaxf(acc[c * 4 + 0], 0.0f);
        o.y = fmaxf(acc[c * 4 + 1], 0.0f);
        o.z = fmaxf(acc[c * 4 + 2], 0.0f);
        o.w = fmaxf(acc[c * 4 + 3], 0.0f);
        *reinterpret_cast<float4*>(op + c * 4) = o;
    }
}

extern "C" void kernel_launch(void* const* d_in, const int* in_sizes, int n_in,
                              void* d_out, int out_size, void* d_ws, size_t ws_size,
                              hipStream_t stream) {
    const float* x = (const float*)d_in[0];   // [16384, 4096]
    const float* k = (const float*)d_in[1];   // [64, 64, 64]
    float* out = (float*)d_out;

    const int rows_total = in_sizes[0] / C_DIM;                    // 16384
    const int grid = (rows_total / ROWS_PER_BLOCK) * NGROUP;       // 256*64
    group_dense_kernel<<<grid, THREADS, 0, stream>>>(x, k, out);
}

// Round 4
// 140.035 us; speedup vs baseline: 1.8175x; 1.8175x over previous
//
#include <hip/hip_runtime.h>

// GroupDense: y[row, g*64+v] = relu( sum_u x[row, g*64+u] * K[g, u, v] )
// x: [16384, 4096] fp32, K: [64, 64, 64] fp32, out: [16384, 4096] fp32.
//
// Round-2 structure + 8x8 micro-tile (1.0 B LDS traffic per FMA, all b128).
// Block = 256 threads = 4 waves, 256 rows x 1 group.
//   Xs: [256 rows][64 f], 16B-chunk XOR swizzle (slot = chunk ^ (row&15))
//       staged via global_load_lds with pre-swizzled per-lane source.
//   Ks: [64 u][64 v] linear (kv reads are 2-way bank-aliased = free).
// Thread = (vg 0..7, rw 0..31): rows rw+32j (j=0..7), cols vg*8..vg*8+7.
// Per 4-u step: 8 xv + 8 kv ds_read_b128 -> 256 FMAs.
// Stores: full 256B per row completed by adjacent instruction pair (exact
// WRITE_SIZE; round-3's 64B/row quarters caused 1.7x write amplification).

constexpr int C_DIM = 4096;
constexpr int NGROUP = 64;
constexpr int ROWS_PER_BLOCK = 256;
constexpr int THREADS = 256;

typedef __attribute__((address_space(3))) void lds_void_t;
typedef const __attribute__((address_space(1))) void gbl_void_t;

__global__ __launch_bounds__(THREADS, 2) void group_dense_kernel(
    const float* __restrict__ x,
    const float* __restrict__ k,
    float* __restrict__ out)
{
    __shared__ float Xs[ROWS_PER_BLOCK * 64]; // 64 KiB
    __shared__ float Ks[64 * 64];             // 16 KiB

    const int bid = blockIdx.x;
    const int g = bid & (NGROUP - 1);
    const int row0 = (bid >> 6) * ROWS_PER_BLOCK;
    const int tid = threadIdx.x;
    const int lane = tid & 63;
    const int wave = tid >> 6;      // 0..3

    // ---- stage x: wave w owns rows [w*64, w*64+64), 16 calls x 4 rows ----
    {
        const int l4 = lane >> 4;    // row within 4-row call
        const int ch = lane & 15;    // dest chunk slot within row
        #pragma unroll
        for (int c = 0; c < 16; ++c) {
            const int rl = wave * 64 + c * 4 + l4;          // local row
            const int chunk = ch ^ (rl & 15);               // pre-swizzled src
            const float* src = x + (size_t)(row0 + rl) * C_DIM + g * 64 + chunk * 4;
            float* dst = &Xs[(wave * 64 + c * 4) * 64];     // wave-uniform, linear
            __builtin_amdgcn_global_load_lds((gbl_void_t*)src, (lds_void_t*)dst, 16, 0, 0);
        }
        // ---- stage K[g]: 4 calls x 1 KiB per wave, fully linear ----
        #pragma unroll
        for (int c = 0; c < 4; ++c) {
            const float* src = k + (size_t)g * 4096 + (wave * 4 + c) * 256 + lane * 4;
            float* dst = &Ks[(wave * 4 + c) * 256];
            __builtin_amdgcn_global_load_lds((gbl_void_t*)src, (lds_void_t*)dst, 16, 0, 0);
        }
    }
    __syncthreads();

    // ---- compute: thread = (vg, rw); rows rw+32j (j=0..7), cols vg*8.. ----
    const int vg = tid & 7;
    const int rw = tid >> 3;        // 0..31

    float acc[8][8] = {};

    // per-row swizzled base (float index): r*64 + (r&15)*4, r&15 == rw&15
    int xbase[8];
    #pragma unroll
    for (int j = 0; j < 8; ++j) {
        const int r = rw + 32 * j;
        xbase[j] = r * 64 + (r & 15) * 4;
    }

    #pragma unroll
    for (int s0 = 0; s0 < 16; ++s0) {       // u chunk = [4*s0, 4*s0+4)
        float kv[4][8];
        #pragma unroll
        for (int i = 0; i < 4; ++i) {
            const float4 a = *reinterpret_cast<const float4*>(
                &Ks[(s0 * 4 + i) * 64 + vg * 8]);
            const float4 b = *reinterpret_cast<const float4*>(
                &Ks[(s0 * 4 + i) * 64 + vg * 8 + 4]);
            kv[i][0] = a.x; kv[i][1] = a.y; kv[i][2] = a.z; kv[i][3] = a.w;
            kv[i][4] = b.x; kv[i][5] = b.y; kv[i][6] = b.z; kv[i][7] = b.w;
        }
        float xv[8][4];
        #pragma unroll
        for (int j = 0; j < 8; ++j) {
            const float4 t = *reinterpret_cast<const float4*>(
                &Xs[xbase[j] ^ (s0 * 4)]);
            xv[j][0] = t.x; xv[j][1] = t.y; xv[j][2] = t.z; xv[j][3] = t.w;
        }
        #pragma unroll
        for (int j = 0; j < 8; ++j)
            #pragma unroll
            for (int i = 0; i < 4; ++i)
                #pragma unroll
                for (int c = 0; c < 8; ++c)
                    acc[j][c] = fmaf(xv[j][i], kv[i][c], acc[j][c]);
    }

    // ---- ReLU + float4 stores: per j, 8 rows x 256B completed pairwise ----
    #pragma unroll
    for (int j = 0; j < 8; ++j) {
        const int r = rw + 32 * j;
        float* op = out + (size_t)(row0 + r) * C_DIM + g * 64 + vg * 8;
        #pragma unroll
        for (int h = 0; h < 2; ++h) {
            float4 o;
            o.x = fmaxf(acc[j][h * 4 + 0], 0.0f);
            o.y = fmaxf(acc[j][h * 4 + 1], 0.0f);
            o.z = fmaxf(acc[j][h * 4 + 2], 0.0f);
            o.w = fmaxf(acc[j][h * 4 + 3], 0.0f);
            *reinterpret_cast<float4*>(op + h * 4) = o;
        }
    }
}

extern "C" void kernel_launch(void* const* d_in, const int* in_sizes, int n_in,
                              void* d_out, int out_size, void* d_ws, size_t ws_size,
                              hipStream_t stream) {
    const float* x = (const float*)d_in[0];   // [16384, 4096]
    const float* k = (const float*)d_in[1];   // [64, 64, 64]
    float* out = (float*)d_out;

    const int rows_total = in_sizes[0] / C_DIM;                    // 16384
    const int grid = (rows_total / ROWS_PER_BLOCK) * NGROUP;       // 64*64 = 4096
    group_dense_kernel<<<grid, THREADS, 0, stream>>>(x, k, out);
}

// Round 5
// 137.890 us; speedup vs baseline: 1.8457x; 1.0156x over previous
//
#include <hip/hip_runtime.h>
#include <hip/hip_bf16.h>

// GroupDense via bf16 MFMA: y[r, g*64+v] = relu( sum_u x[r, g*64+u] K[g,u,v] )
// x: [16384, 4096] fp32, K: [64,64,64] fp32, out fp32. Harness absmax
// threshold 4.94e-2 (bf16-grade) -> convert operands to bf16 in-register,
// accumulate fp32 in MFMA. No LDS, no barriers.
//
// mfma_f32_16x16x32_bf16 layouts (guide-verified m89/m92):
//   A frag: lane l holds A[l&15][8*(l>>4)+j], j=0..7 (contiguous k)
//   B frag: lane l holds B[8*(l>>4)+j][l&15]
//   C/D:    lane l reg r -> row (l>>4)*4+r, col l&15
// A = x row-tile (16 rows x 32 u): 2 float4 global loads per chunk, cvt_pk.
// B = K[g] columns: 64 scalar loads/lane once per block (L2-resident), cvt.
// Stores: per row, 4 adjacent 64B instructions complete the 256B line (exact
// WRITE_SIZE; learned in round 3 that split-in-time quarters cost 1.7x).

typedef short bf16x8 __attribute__((ext_vector_type(8)));
typedef float f32x4 __attribute__((ext_vector_type(4)));

constexpr int C_DIM = 4096;
constexpr int NGROUP = 64;
constexpr int ROWS_PER_BLOCK = 256;
constexpr int THREADS = 256;

union BF8 { bf16x8 v; __hip_bfloat162 h[4]; };

static __device__ inline bf16x8 pack8(const float4& a, const float4& b) {
    BF8 u;
    u.h[0] = __float22bfloat162_rn(float2{a.x, a.y});
    u.h[1] = __float22bfloat162_rn(float2{a.z, a.w});
    u.h[2] = __float22bfloat162_rn(float2{b.x, b.y});
    u.h[3] = __float22bfloat162_rn(float2{b.z, b.w});
    return u.v;
}

__global__ __launch_bounds__(THREADS, 4) void group_dense_kernel(
    const float* __restrict__ x,
    const float* __restrict__ k,
    float* __restrict__ out)
{
    const int bid = blockIdx.x;
    const int g = bid & (NGROUP - 1);
    const int row0 = (bid >> 6) * ROWS_PER_BLOCK;
    const int tid = threadIdx.x;
    const int wave = tid >> 6;
    const int lane = tid & 63;
    const int lr = lane & 15;   // A row-in-tile / B col-in-coltile
    const int lk = lane >> 4;   // k-group 0..3

    // ---- B fragments: Bf[c][h], elem j = K[g][32h+8lk+j][16c+lr] ----
    bf16x8 Bf[4][2];
    {
        const float* kb = k + (size_t)g * 4096 + lr;
        #pragma unroll
        for (int c = 0; c < 4; ++c) {
            #pragma unroll
            for (int h = 0; h < 2; ++h) {
                float t[8];
                #pragma unroll
                for (int j = 0; j < 8; ++j)
                    t[j] = kb[(32 * h + 8 * lk + j) * 64 + 16 * c];
                BF8 u;
                u.h[0] = __float22bfloat162_rn(float2{t[0], t[1]});
                u.h[1] = __float22bfloat162_rn(float2{t[2], t[3]});
                u.h[2] = __float22bfloat162_rn(float2{t[4], t[5]});
                u.h[3] = __float22bfloat162_rn(float2{t[6], t[7]});
                Bf[c][h] = u.v;
            }
        }
    }

    // ---- 4 row-tiles of 16 per wave, software-pipelined (prefetch t+1) ----
    const int t0 = wave * 4;
    const float* xb = x + (size_t)row0 * C_DIM + g * 64 + 8 * lk;

    float4 A0, A1, A2, A3, N0, N1, N2, N3;
    {
        const float4* p = (const float4*)(xb + (size_t)(t0 * 16 + lr) * C_DIM);
        A0 = p[0]; A1 = p[1]; A2 = p[8]; A3 = p[9];   // u: 8lk..+7, 32+8lk..+7
    }

    #pragma unroll
    for (int t = 0; t < 4; ++t) {
        if (t < 3) {
            const float4* p = (const float4*)(
                xb + (size_t)((t0 + t + 1) * 16 + lr) * C_DIM);
            N0 = p[0]; N1 = p[1]; N2 = p[8]; N3 = p[9];
        }

        const bf16x8 a0 = pack8(A0, A1);   // u-chunk h=0
        const bf16x8 a1 = pack8(A2, A3);   // u-chunk h=1

        f32x4 ac0 = {0.f, 0.f, 0.f, 0.f};
        f32x4 ac1 = ac0, ac2 = ac0, ac3 = ac0;
        ac0 = __builtin_amdgcn_mfma_f32_16x16x32_bf16(a0, Bf[0][0], ac0, 0, 0, 0);
        ac1 = __builtin_amdgcn_mfma_f32_16x16x32_bf16(a0, Bf[1][0], ac1, 0, 0, 0);
        ac2 = __builtin_amdgcn_mfma_f32_16x16x32_bf16(a0, Bf[2][0], ac2, 0, 0, 0);
        ac3 = __builtin_amdgcn_mfma_f32_16x16x32_bf16(a0, Bf[3][0], ac3, 0, 0, 0);
        ac0 = __builtin_amdgcn_mfma_f32_16x16x32_bf16(a1, Bf[0][1], ac0, 0, 0, 0);
        ac1 = __builtin_amdgcn_mfma_f32_16x16x32_bf16(a1, Bf[1][1], ac1, 0, 0, 0);
        ac2 = __builtin_amdgcn_mfma_f32_16x16x32_bf16(a1, Bf[2][1], ac2, 0, 0, 0);
        ac3 = __builtin_amdgcn_mfma_f32_16x16x32_bf16(a1, Bf[3][1], ac3, 0, 0, 0);

        // ---- ReLU + stores: D row (l>>4)*4+r, col 16c+lr ----
        float* ob = out + (size_t)(row0 + (t0 + t) * 16 + 4 * lk) * C_DIM
                    + g * 64 + lr;
        #pragma unroll
        for (int r = 0; r < 4; ++r) {
            const size_t ro = (size_t)r * C_DIM;
            ob[ro +  0] = fmaxf(ac0[r], 0.0f);
            ob[ro + 16] = fmaxf(ac1[r], 0.0f);
            ob[ro + 32] = fmaxf(ac2[r], 0.0f);
            ob[ro + 48] = fmaxf(ac3[r], 0.0f);
        }

        if (t < 3) { A0 = N0; A1 = N1; A2 = N2; A3 = N3; }
    }
}

extern "C" void kernel_launch(void* const* d_in, const int* in_sizes, int n_in,
                              void* d_out, int out_size, void* d_ws, size_t ws_size,
                              hipStream_t stream) {
    const float* x = (const float*)d_in[0];   // [16384, 4096]
    const float* k = (const float*)d_in[1];   // [64, 64, 64]
    float* out = (float*)d_out;

    const int rows_total = in_sizes[0] / C_DIM;                 // 16384
    const int grid = (rows_total / ROWS_PER_BLOCK) * NGROUP;    // 64*64 = 4096
    group_dense_kernel<<<grid, THREADS, 0, stream>>>(x, k, out);
}

// Round 6
// 126.345 us; speedup vs baseline: 2.0144x; 1.0914x over previous
//
#include <hip/hip_runtime.h>
#include <hip/hip_bf16.h>

// GroupDense via bf16 MFMA, latency-hiding structure:
//   y[r, g*64+v] = relu( sum_u x[r, g*64+u] * K[g,u,v] )
// x: [16384, 4096] fp32, K: [64,64,64] fp32, out fp32 (absmax thr 4.9e-2).
//
// Block = 256 thr = 4 waves, 512 rows x 1 group. Per wave: 8 tiles x 16 rows.
//  - K[g]: converted ONCE to bf16, stored transposed [v][u] in LDS with
//    8-chunk XOR swizzle (slot = cu ^ (v&7)); B-frags = 8 ds_read_b128,
//    conflict-free, held in 32 VGPRs. One barrier total.
//  - x: global_load_lds DMA into PER-WAVE private double buffers (each wave
//    stages the rows it computes) -> NO barriers in main loop; counted
//    s_waitcnt vmcnt(4) keeps next tile's 4 DMAs in flight during compute.
//  - A-frags: 4 ds_read_b128 from 16B-chunk XOR-swizzled tile + cvt_pk.
//  - mfma_f32_16x16x32_bf16 (layouts verified in r5, absmax 0.0156):
//    A: lane l -> A[l&15][8*(l>>4)+j]; B: K[8*(l>>4)+j][l&15(+16c)]
//    C/D: lane l reg r -> row 4*(l>>4)+r, col l&15.
//  - stores: full 256B/row completed by adjacent instrs (exact WRITE_SIZE).

typedef short bf16x8 __attribute__((ext_vector_type(8)));
typedef float f32x4 __attribute__((ext_vector_type(4)));

constexpr int C_DIM = 4096;
constexpr int NGROUP = 64;
constexpr int ROWS_PER_BLOCK = 512;   // 128 rows/wave = 8 tiles of 16
constexpr int THREADS = 256;
constexpr int NT = 8;

typedef __attribute__((address_space(3))) void lds_void_t;
typedef const __attribute__((address_space(1))) void gbl_void_t;

union BF8 { bf16x8 v; __hip_bfloat162 h[4]; };

static __device__ inline bf16x8 pack8(const float4& a, const float4& b) {
    BF8 u;
    u.h[0] = __float22bfloat162_rn(float2{a.x, a.y});
    u.h[1] = __float22bfloat162_rn(float2{a.z, a.w});
    u.h[2] = __float22bfloat162_rn(float2{b.x, b.y});
    u.h[3] = __float22bfloat162_rn(float2{b.z, b.w});
    return u.v;
}

__global__ __launch_bounds__(THREADS, 4) void group_dense_kernel(
    const float* __restrict__ x,
    const float* __restrict__ k,
    float* __restrict__ out)
{
    __shared__ float Xs[8 * 1024];          // 32 KiB: wave w -> [w*2048, +2048)
    __shared__ __hip_bfloat16 KT[64 * 64];  // 8 KiB transposed+swizzled bf16

    const int bid = blockIdx.x;
    const int g = bid & (NGROUP - 1);
    const int row0 = (bid >> 6) * ROWS_PER_BLOCK;
    const int tid = threadIdx.x;
    const int wave = tid >> 6;
    const int lane = tid & 63;
    const int lr = lane & 15;
    const int lk = lane >> 4;

    // ---- per-lane staging constants (call c stages tile rows 4c..4c+3) ----
    // dest is linear: lane l -> row l>>4, chunk l&15 of the 4-row slab;
    // source column is pre-swizzled: chunk_src = ch ^ row_in_tile.
    const int l4 = lane >> 4;
    const int ch = lane & 15;
    const float* xsrc[4];
    #pragma unroll
    for (int c = 0; c < 4; ++c) {
        const int r16 = c * 4 + l4;          // row within 16-row tile
        xsrc[c] = x + (size_t)(row0 + wave * 128 + r16) * C_DIM
                  + g * 64 + ((ch ^ r16) * 4);
    }
    float* const sb0 = &Xs[wave * 2048];
    float* const sb1 = &Xs[wave * 2048 + 1024];

#define STAGE(BUF, T) do {                                                   \
    const size_t roff_ = (size_t)(T) * 16 * C_DIM;                           \
    _Pragma("unroll")                                                        \
    for (int c_ = 0; c_ < 4; ++c_)                                           \
        __builtin_amdgcn_global_load_lds((gbl_void_t*)(xsrc[c_] + roff_),    \
            (lds_void_t*)((BUF) + c_ * 256), 16, 0, 0);                      \
} while (0)

    // ---- issue tile-0 DMA first, overlap with K prologue ----
    STAGE(sb0, 0);

    // ---- K[g] -> KT (bf16, transposed [v][u], 16B-chunk XOR swizzle) ----
    {
        const int v = tid & 63;
        const int c0 = tid >> 6;             // u-chunk 0..3 (and +4)
        #pragma unroll
        for (int cc = 0; cc < 2; ++cc) {
            const int c = c0 + cc * 4;       // u-chunk 0..7 (8 u's each)
            const float* kp = k + (size_t)g * 4096 + (size_t)(8 * c) * 64 + v;
            float t[8];
            #pragma unroll
            for (int j = 0; j < 8; ++j) t[j] = kp[j * 64];  // coalesced in v
            BF8 u;
            u.h[0] = __float22bfloat162_rn(float2{t[0], t[1]});
            u.h[1] = __float22bfloat162_rn(float2{t[2], t[3]});
            u.h[2] = __float22bfloat162_rn(float2{t[4], t[5]});
            u.h[3] = __float22bfloat162_rn(float2{t[6], t[7]});
            *reinterpret_cast<bf16x8*>(&KT[v * 64 + ((c ^ (v & 7)) * 8)]) = u.v;
        }
    }
    __syncthreads();   // only barrier in the kernel

    // ---- B fragments from KT: 8 conflict-free ds_read_b128 ----
    bf16x8 Bf[4][2];
    #pragma unroll
    for (int c = 0; c < 4; ++c) {
        #pragma unroll
        for (int h = 0; h < 2; ++h) {
            const int v = 16 * c + lr;
            const int cu = 4 * h + lk;
            Bf[c][h] = *reinterpret_cast<const bf16x8*>(
                &KT[v * 64 + ((cu ^ (v & 7)) * 8)]);
        }
    }

    // ---- main loop: counted-vmcnt pipeline, no barriers ----
    const int s0 = ((2 * lk + 0) ^ lr) * 4;
    const int s1 = ((2 * lk + 1) ^ lr) * 4;
    const int s2 = ((8 + 2 * lk + 0) ^ lr) * 4;
    const int s3 = ((8 + 2 * lk + 1) ^ lr) * 4;

    #pragma unroll
    for (int t = 0; t < NT; ++t) {
        float* const cur = (t & 1) ? sb1 : sb0;
        float* const nxt = (t & 1) ? sb0 : sb1;
        if (t + 1 < NT) {
            STAGE(nxt, t + 1);
            asm volatile("s_waitcnt vmcnt(4)" ::: "memory");  // tile t arrived
        } else {
            asm volatile("s_waitcnt vmcnt(0)" ::: "memory");
        }
        __builtin_amdgcn_sched_barrier(0);

        const float* row = cur + lr * 64;
        const float4 c0 = *reinterpret_cast<const float4*>(row + s0);
        const float4 c1 = *reinterpret_cast<const float4*>(row + s1);
        const float4 c2 = *reinterpret_cast<const float4*>(row + s2);
        const float4 c3 = *reinterpret_cast<const float4*>(row + s3);
        const bf16x8 a0 = pack8(c0, c1);   // u 0..31 slice (this lane's 8)
        const bf16x8 a1 = pack8(c2, c3);   // u 32..63 slice

        f32x4 ac0 = {0.f, 0.f, 0.f, 0.f};
        f32x4 ac1 = ac0, ac2 = ac0, ac3 = ac0;
        ac0 = __builtin_amdgcn_mfma_f32_16x16x32_bf16(a0, Bf[0][0], ac0, 0, 0, 0);
        ac1 = __builtin_amdgcn_mfma_f32_16x16x32_bf16(a0, Bf[1][0], ac1, 0, 0, 0);
        ac2 = __builtin_amdgcn_mfma_f32_16x16x32_bf16(a0, Bf[2][0], ac2, 0, 0, 0);
        ac3 = __builtin_amdgcn_mfma_f32_16x16x32_bf16(a0, Bf[3][0], ac3, 0, 0, 0);
        ac0 = __builtin_amdgcn_mfma_f32_16x16x32_bf16(a1, Bf[0][1], ac0, 0, 0, 0);
        ac1 = __builtin_amdgcn_mfma_f32_16x16x32_bf16(a1, Bf[1][1], ac1, 0, 0, 0);
        ac2 = __builtin_amdgcn_mfma_f32_16x16x32_bf16(a1, Bf[2][1], ac2, 0, 0, 0);
        ac3 = __builtin_amdgcn_mfma_f32_16x16x32_bf16(a1, Bf[3][1], ac3, 0, 0, 0);

        // ---- ReLU + stores: row 4lk+r, cols lr+16c (256B/row pairwise) ----
        float* ob = out + (size_t)(row0 + wave * 128 + t * 16 + 4 * lk) * C_DIM
                    + g * 64 + lr;
        #pragma unroll
        for (int r = 0; r < 4; ++r) {
            const size_t ro = (size_t)r * C_DIM;
            ob[ro +  0] = fmaxf(ac0[r], 0.0f);
            ob[ro + 16] = fmaxf(ac1[r], 0.0f);
            ob[ro + 32] = fmaxf(ac2[r], 0.0f);
            ob[ro + 48] = fmaxf(ac3[r], 0.0f);
        }
    }
#undef STAGE
}

extern "C" void kernel_launch(void* const* d_in, const int* in_sizes, int n_in,
                              void* d_out, int out_size, void* d_ws, size_t ws_size,
                              hipStream_t stream) {
    const float* x = (const float*)d_in[0];   // [16384, 4096]
    const float* k = (const float*)d_in[1];   // [64, 64, 64]
    float* out = (float*)d_out;

    const int rows_total = in_sizes[0] / C_DIM;                  // 16384
    const int grid = (rows_total / ROWS_PER_BLOCK) * NGROUP;     // 32*64 = 2048
    group_dense_kernel<<<grid, THREADS, 0, stream>>>(x, k, out);
}

// Round 7
// 119.583 us; speedup vs baseline: 2.1283x; 1.0565x over previous
//
#include <hip/hip_runtime.h>
#include <hip/hip_bf16.h>

// GroupDense via bf16 MFMA, depth-2 latency-hiding pipeline:
//   y[r, g*64+v] = relu( sum_u x[r, g*64+u] * K[g,u,v] )
// x: [16384, 4096] fp32, K: [64,64,64] fp32, out fp32 (absmax thr 4.9e-2).
//
// Block = 128 thr = 2 waves, 256 rows x 1 group; per wave 8 tiles x 16 rows.
// LDS 32 KB -> 5 blocks/CU (10 waves/CU), each wave an independent DMA queue.
//  - K[g]: once per block -> bf16 transposed [v][u], 8-chunk XOR swizzle;
//    B-frags = 8 conflict-free ds_read_b128 (32 VGPRs). One barrier total.
//  - x: global_load_lds into per-wave TRIPLE-buffered 4 KB tiles, prefetch
//    depth 2; counted s_waitcnt vmcnt(N) with N derived from exact issue
//    order (D=4 DMAs/tile, S=16 stores/tile) so waits NEVER block on the
//    previous tiles' stores (r6's vmcnt(4) forced a store drain every tile):
//    order D0 D1 D2 s0 D3 s1 D4 s2 D5 s3 D6 s4 D7 s5 s6 ->
//    waits: t0=8, t1=24, t2..t5=40, t6=36, t7=32.
//  - mfma_f32_16x16x32_bf16, layouts verified r5/r6 (absmax 0.0156).
//  - stores: full 256B/row completed by adjacent instrs (exact WRITE_SIZE).

typedef short bf16x8 __attribute__((ext_vector_type(8)));
typedef float f32x4 __attribute__((ext_vector_type(4)));

constexpr int C_DIM = 4096;
constexpr int NGROUP = 64;
constexpr int ROWS_PER_BLOCK = 256;   // 2 waves * 8 tiles * 16 rows
constexpr int THREADS = 128;
constexpr int NT = 8;

typedef __attribute__((address_space(3))) void lds_void_t;
typedef const __attribute__((address_space(1))) void gbl_void_t;

union BF8 { bf16x8 v; __hip_bfloat162 h[4]; };

static __device__ inline bf16x8 pack8(const float4& a, const float4& b) {
    BF8 u;
    u.h[0] = __float22bfloat162_rn(float2{a.x, a.y});
    u.h[1] = __float22bfloat162_rn(float2{a.z, a.w});
    u.h[2] = __float22bfloat162_rn(float2{b.x, b.y});
    u.h[3] = __float22bfloat162_rn(float2{b.z, b.w});
    return u.v;
}

__global__ __launch_bounds__(THREADS, 3) void group_dense_kernel(
    const float* __restrict__ x,
    const float* __restrict__ k,
    float* __restrict__ out)
{
    __shared__ float Xs[2 * 3 * 1024];      // 24 KiB: wave w -> [w*3072, +3072)
    __shared__ __hip_bfloat16 KT[64 * 64];  // 8 KiB transposed+swizzled bf16

    const int bid = blockIdx.x;
    const int g = bid & (NGROUP - 1);
    const int row0 = (bid >> 6) * ROWS_PER_BLOCK;
    const int tid = threadIdx.x;
    const int wave = tid >> 6;              // 0..1
    const int lane = tid & 63;
    const int lr = lane & 15;
    const int lk = lane >> 4;

    // ---- per-lane staging constants (call c stages tile rows 4c..4c+3) ----
    const int l4 = lane >> 4;
    const int ch = lane & 15;
    const float* xsrc[4];
    #pragma unroll
    for (int c = 0; c < 4; ++c) {
        const int r16 = c * 4 + l4;          // row within 16-row tile
        xsrc[c] = x + (size_t)(row0 + wave * 128 + r16) * C_DIM
                  + g * 64 + ((ch ^ r16) * 4);
    }
    float* const sb[3] = { &Xs[wave * 3072],
                           &Xs[wave * 3072 + 1024],
                           &Xs[wave * 3072 + 2048] };

#define STAGE(BUF, T) do {                                                   \
    const size_t roff_ = (size_t)(T) * 16 * C_DIM;                           \
    _Pragma("unroll")                                                        \
    for (int c_ = 0; c_ < 4; ++c_)                                           \
        __builtin_amdgcn_global_load_lds((gbl_void_t*)(xsrc[c_] + roff_),    \
            (lds_void_t*)((BUF) + c_ * 256), 16, 0, 0);                      \
} while (0)

    // ---- prologue: 2 tiles in flight before anything else ----
    STAGE(sb[0], 0);
    STAGE(sb[1], 1);

    // ---- K[g] -> KT (bf16, transposed [v][u], 8-chunk XOR swizzle) ----
    {
        const int v = tid & 63;
        const int c0 = tid >> 6;             // 0..1
        #pragma unroll
        for (int cc = 0; cc < 4; ++cc) {
            const int c = c0 + cc * 2;       // u-chunk 0..7 (8 u's each)
            const float* kp = k + (size_t)g * 4096 + (size_t)(8 * c) * 64 + v;
            float t[8];
            #pragma unroll
            for (int j = 0; j < 8; ++j) t[j] = kp[j * 64];  // coalesced in v
            BF8 u;
            u.h[0] = __float22bfloat162_rn(float2{t[0], t[1]});
            u.h[1] = __float22bfloat162_rn(float2{t[2], t[3]});
            u.h[2] = __float22bfloat162_rn(float2{t[4], t[5]});
            u.h[3] = __float22bfloat162_rn(float2{t[6], t[7]});
            *reinterpret_cast<bf16x8*>(&KT[v * 64 + ((c ^ (v & 7)) * 8)]) = u.v;
        }
    }
    __syncthreads();   // only barrier in the kernel

    // ---- B fragments from KT: 8 conflict-free ds_read_b128 ----
    bf16x8 Bf[4][2];
    #pragma unroll
    for (int c = 0; c < 4; ++c) {
        #pragma unroll
        for (int h = 0; h < 2; ++h) {
            const int v = 16 * c + lr;
            const int cu = 4 * h + lk;
            Bf[c][h] = *reinterpret_cast<const bf16x8*>(
                &KT[v * 64 + ((cu ^ (v & 7)) * 8)]);
        }
    }

    // ---- main loop: depth-2 counted-vmcnt pipeline, no barriers ----
    const int s0 = ((2 * lk + 0) ^ lr) * 4;
    const int s1 = ((2 * lk + 1) ^ lr) * 4;
    const int s2 = ((8 + 2 * lk + 0) ^ lr) * 4;
    const int s3 = ((8 + 2 * lk + 1) ^ lr) * 4;

    #pragma unroll
    for (int t = 0; t < NT; ++t) {
        if (t + 2 < NT) STAGE(sb[(t + 2) % 3], t + 2);

        // wait for DMA(t); N = ops issued after D(t) -> never blocks on
        // stores younger than ~2 iterations (see header comment).
        if      (t == 0) asm volatile("s_waitcnt vmcnt(8)"  ::: "memory");
        else if (t == 1) asm volatile("s_waitcnt vmcnt(24)" ::: "memory");
        else if (t == 6) asm volatile("s_waitcnt vmcnt(36)" ::: "memory");
        else if (t == 7) asm volatile("s_waitcnt vmcnt(32)" ::: "memory");
        else             asm volatile("s_waitcnt vmcnt(40)" ::: "memory");
        __builtin_amdgcn_sched_barrier(0);

        const float* row = sb[t % 3] + lr * 64;
        const float4 c0 = *reinterpret_cast<const float4*>(row + s0);
        const float4 c1 = *reinterpret_cast<const float4*>(row + s1);
        const float4 c2 = *reinterpret_cast<const float4*>(row + s2);
        const float4 c3 = *reinterpret_cast<const float4*>(row + s3);
        const bf16x8 a0 = pack8(c0, c1);   // u 0..31 slice (this lane's 8)
        const bf16x8 a1 = pack8(c2, c3);   // u 32..63 slice

        f32x4 ac0 = {0.f, 0.f, 0.f, 0.f};
        f32x4 ac1 = ac0, ac2 = ac0, ac3 = ac0;
        ac0 = __builtin_amdgcn_mfma_f32_16x16x32_bf16(a0, Bf[0][0], ac0, 0, 0, 0);
        ac1 = __builtin_amdgcn_mfma_f32_16x16x32_bf16(a0, Bf[1][0], ac1, 0, 0, 0);
        ac2 = __builtin_amdgcn_mfma_f32_16x16x32_bf16(a0, Bf[2][0], ac2, 0, 0, 0);
        ac3 = __builtin_amdgcn_mfma_f32_16x16x32_bf16(a0, Bf[3][0], ac3, 0, 0, 0);
        ac0 = __builtin_amdgcn_mfma_f32_16x16x32_bf16(a1, Bf[0][1], ac0, 0, 0, 0);
        ac1 = __builtin_amdgcn_mfma_f32_16x16x32_bf16(a1, Bf[1][1], ac1, 0, 0, 0);
        ac2 = __builtin_amdgcn_mfma_f32_16x16x32_bf16(a1, Bf[2][1], ac2, 0, 0, 0);
        ac3 = __builtin_amdgcn_mfma_f32_16x16x32_bf16(a1, Bf[3][1], ac3, 0, 0, 0);

        // ---- ReLU + stores: row 4lk+r, cols lr+16c (256B/row pairwise) ----
        float* ob = out + (size_t)(row0 + wave * 128 + t * 16 + 4 * lk) * C_DIM
                    + g * 64 + lr;
        #pragma unroll
        for (int r = 0; r < 4; ++r) {
            const size_t ro = (size_t)r * C_DIM;
            ob[ro +  0] = fmaxf(ac0[r], 0.0f);
            ob[ro + 16] = fmaxf(ac1[r], 0.0f);
            ob[ro + 32] = fmaxf(ac2[r], 0.0f);
            ob[ro + 48] = fmaxf(ac3[r], 0.0f);
        }
    }
#undef STAGE
}

extern "C" void kernel_launch(void* const* d_in, const int* in_sizes, int n_in,
                              void* d_out, int out_size, void* d_ws, size_t ws_size,
                              hipStream_t stream) {
    const float* x = (const float*)d_in[0];   // [16384, 4096]
    const float* k = (const float*)d_in[1];   // [64, 64, 64]
    float* out = (float*)d_out;

    const int rows_total = in_sizes[0] / C_DIM;                  // 16384
    const int grid = (rows_total / ROWS_PER_BLOCK) * NGROUP;     // 64*64 = 4096
    group_dense_kernel<<<grid, THREADS, 0, stream>>>(x, k, out);
}

// Round 9
// 106.478 us; speedup vs baseline: 2.3902x; 1.1231x over previous
//
#include <hip/hip_runtime.h>
#include <hip/hip_bf16.h>

// GroupDense via bf16 MFMA, operand-swapped (y^T = K^T x^T) register pipeline:
//   y[r, g*64+v] = relu( sum_u x[r, g*64+u] * K[g,u,v] )
// x: [16384, 4096] fp32, K: [64,64,64] fp32, out fp32 (absmax thr 4.9e-2).
//
// Key trick: A-frag (lane: row=l&15, k=8*(l>>4)+j) and B-frag (lane:
// k=8*(l>>4)+j, col=l&15) are mirror layouts, so swapping MFMA operands
// (A := K^T fragment, B := x fragment) reuses the exact same register data
// but flips the C/D layout to row-major-per-lane: lane l, reg q holds
// y[row=l&15][v=16c+4*(l>>4)+q] -> ONE float4 store per col-tile
// (16 dword stores/tile in r5-r7 -> 4 dwordx4 stores).
//
// x: loaded global->register (32B contiguous per lane = its own row), NO LDS,
//    depth-2 register pipeline; compiler emits exact counted vmcnt waits,
//    structure pinned with sched_barrier(0) at phase boundaries.
// K[g]: once per block -> bf16 transposed KT[v][u], 8-chunk XOR swizzle;
//    A-frags = 8 conflict-free ds_read_b128. One barrier total.
// out: nontemporal f32x4 stores (never re-read; avoid evicting x from L3 --
//    observed FETCH ~132MB < 268MB means x is ~L3-resident across replays).

typedef short bf16x8 __attribute__((ext_vector_type(8)));
typedef float f32x4 __attribute__((ext_vector_type(4)));

constexpr int C_DIM = 4096;
constexpr int NGROUP = 64;
constexpr int THREADS = 256;          // 4 waves
constexpr int NT = 8;                 // 16-row tiles per wave
constexpr int ROWS_PER_BLOCK = 4 * NT * 16;   // 512

union BF8 { bf16x8 v; __hip_bfloat162 h[4]; };

static __device__ inline bf16x8 pack8(const float4& a, const float4& b) {
    BF8 u;
    u.h[0] = __float22bfloat162_rn(float2{a.x, a.y});
    u.h[1] = __float22bfloat162_rn(float2{a.z, a.w});
    u.h[2] = __float22bfloat162_rn(float2{b.x, b.y});
    u.h[3] = __float22bfloat162_rn(float2{b.z, b.w});
    return u.v;
}

__global__ __launch_bounds__(THREADS, 3) void group_dense_kernel(
    const float* __restrict__ x,
    const float* __restrict__ k,
    float* __restrict__ out)
{
    __shared__ __hip_bfloat16 KT[64 * 64];   // 8 KiB, transposed + swizzled

    const int bid = blockIdx.x;
    const int g = bid & (NGROUP - 1);
    const int row0 = (bid >> 6) * ROWS_PER_BLOCK;
    const int tid = threadIdx.x;
    const int wave = tid >> 6;
    const int lane = tid & 63;
    const int lr = lane & 15;
    const int lk = lane >> 4;

    // ---- x/out base for this lane (row = row0 + wave*128 + t*16 + lr) ----
    const float* xp = x + (size_t)(row0 + wave * 128 + lr) * C_DIM + g * 64 + 8 * lk;
    float* op = out + (size_t)(row0 + wave * 128 + lr) * C_DIM + g * 64 + 4 * lk;

    float4 buf[3][4];   // all indices compile-time (rule #20)
#define LOADT(SLOT, T) do {                                                   \
    const float4* p_ = (const float4*)(xp + (size_t)(T) * 16 * C_DIM);        \
    buf[SLOT][0] = p_[0];  /* u: 8lk..+3   */                                 \
    buf[SLOT][1] = p_[1];  /* u: 8lk+4..+7 */                                 \
    buf[SLOT][2] = p_[8];  /* u: 32+8lk..  */                                 \
    buf[SLOT][3] = p_[9];                                                     \
} while (0)

    // ---- issue first two tiles' loads before the K prologue ----
    LOADT(0, 0);
    LOADT(1, 1);

    // ---- K[g] -> KT (bf16, transposed [v][u], 8-chunk XOR swizzle) ----
    {
        const int v = tid & 63;
        const int c0 = tid >> 6;             // 0..3
        #pragma unroll
        for (int cc = 0; cc < 2; ++cc) {
            const int c = c0 + cc * 4;       // u-chunk 0..7 (8 u's each)
            const float* kp = k + (size_t)g * 4096 + (size_t)(8 * c) * 64 + v;
            float t[8];
            #pragma unroll
            for (int j = 0; j < 8; ++j) t[j] = kp[j * 64];  // coalesced in v
            BF8 u;
            u.h[0] = __float22bfloat162_rn(float2{t[0], t[1]});
            u.h[1] = __float22bfloat162_rn(float2{t[2], t[3]});
            u.h[2] = __float22bfloat162_rn(float2{t[4], t[5]});
            u.h[3] = __float22bfloat162_rn(float2{t[6], t[7]});
            *reinterpret_cast<bf16x8*>(&KT[v * 64 + ((c ^ (v & 7)) * 8)]) = u.v;
        }
    }
    __syncthreads();   // only barrier in the kernel

    // ---- A fragments (K^T): lane l -> A[v=16c+lr][u=8lk+j+32h] ----
    bf16x8 Af[4][2];
    #pragma unroll
    for (int c = 0; c < 4; ++c) {
        #pragma unroll
        for (int h = 0; h < 2; ++h) {
            const int v = 16 * c + lr;
            const int cu = 4 * h + lk;
            Af[c][h] = *reinterpret_cast<const bf16x8*>(
                &KT[v * 64 + ((cu ^ (v & 7)) * 8)]);
        }
    }

    // ---- main loop: depth-2 register pipeline ----
    #pragma unroll
    for (int t = 0; t < NT; ++t) {
        if (t + 2 < NT) LOADT((t + 2) % 3, t + 2);
        __builtin_amdgcn_sched_barrier(0);

        const bf16x8 b0 = pack8(buf[t % 3][0], buf[t % 3][1]);  // u 0..31
        const bf16x8 b1 = pack8(buf[t % 3][2], buf[t % 3][3]);  // u 32..63

        f32x4 ac0 = {0.f, 0.f, 0.f, 0.f};
        f32x4 ac1 = ac0, ac2 = ac0, ac3 = ac0;
        // D = A*B = K^T * x^T : lane l, reg q -> y[row lr][16c + 4lk + q]
        ac0 = __builtin_amdgcn_mfma_f32_16x16x32_bf16(Af[0][0], b0, ac0, 0, 0, 0);
        ac1 = __builtin_amdgcn_mfma_f32_16x16x32_bf16(Af[1][0], b0, ac1, 0, 0, 0);
        ac2 = __builtin_amdgcn_mfma_f32_16x16x32_bf16(Af[2][0], b0, ac2, 0, 0, 0);
        ac3 = __builtin_amdgcn_mfma_f32_16x16x32_bf16(Af[3][0], b0, ac3, 0, 0, 0);
        ac0 = __builtin_amdgcn_mfma_f32_16x16x32_bf16(Af[0][1], b1, ac0, 0, 0, 0);
        ac1 = __builtin_amdgcn_mfma_f32_16x16x32_bf16(Af[1][1], b1, ac1, 0, 0, 0);
        ac2 = __builtin_amdgcn_mfma_f32_16x16x32_bf16(Af[2][1], b1, ac2, 0, 0, 0);
        ac3 = __builtin_amdgcn_mfma_f32_16x16x32_bf16(Af[3][1], b1, ac3, 0, 0, 0);

        // ---- ReLU + 4 nontemporal f32x4 stores (row lr, cols 16c+4lk..) ----
        float* ob = op + (size_t)t * 16 * C_DIM;
        #pragma unroll
        for (int c = 0; c < 4; ++c) {
            const f32x4 a = (c == 0) ? ac0 : (c == 1) ? ac1 : (c == 2) ? ac2 : ac3;
            f32x4 o;
            o[0] = fmaxf(a[0], 0.0f);
            o[1] = fmaxf(a[1], 0.0f);
            o[2] = fmaxf(a[2], 0.0f);
            o[3] = fmaxf(a[3], 0.0f);
            __builtin_nontemporal_store(o, reinterpret_cast<f32x4*>(ob + 16 * c));
        }
        __builtin_amdgcn_sched_barrier(0);
    }
#undef LOADT
}

extern "C" void kernel_launch(void* const* d_in, const int* in_sizes, int n_in,
                              void* d_out, int out_size, void* d_ws, size_t ws_size,
                              hipStream_t stream) {
    const float* x = (const float*)d_in[0];   // [16384, 4096]
    const float* k = (const float*)d_in[1];   // [64, 64, 64]
    float* out = (float*)d_out;

    const int rows_total = in_sizes[0] / C_DIM;                  // 16384
    const int grid = (rows_total / ROWS_PER_BLOCK) * NGROUP;     // 32*64 = 2048
    group_dense_kernel<<<grid, THREADS, 0, stream>>>(x, k, out);
}